// Round 8
// baseline (108.298 us; speedup 1.0000x reference)
//
#include <hip/hip_runtime.h>

#define EPS 1e-10f

constexpr int B_ = 64, K_ = 4, M_ = 3, P_ = 65536;
constexpr int THREADS = 256;
constexpr int CHUNK = 2048;                 // pixels per block
constexpr int BPB = P_ / CHUNK;             // 32 -> 2048 blocks
constexpr int NS = 32;                      // sums stride
constexpr int NACC = 29;                    // s0..3 t4..15 u16..27 n28

// Stage 8 planes x 2048 px into LDS. Wave w stages planes 2w,2w+1 as two
// fully-contiguous 8KB bursts: 8 back-to-back global_load_lds (1KB each)
// per plane -> 16 loads in flight per wave, no barrier until all issued.
__device__ __forceinline__ void stage_block(
    const float* __restrict__ pred, const float* __restrict__ inp,
    const int* __restrict__ heart, int b, int px0,
    float (*sbuf)[CHUNK], int wv, int lane)
{
    #pragma unroll
    for (int q = 0; q < 2; ++q) {
        const int pl = wv * 2 + q;
        const float* g;
        if (pl < 4)      g = pred + ((size_t)b * K_ + pl) * P_ + px0;
        else if (pl < 7) g = inp  + ((size_t)b * M_ + (pl - 4)) * P_ + px0;
        else             g = (const float*)(heart + (size_t)b * P_ + px0);
        #pragma unroll
        for (int c = 0; c < CHUNK / 256; ++c)
            __builtin_amdgcn_global_load_lds(g + c * 256 + lane * 4,
                                             &sbuf[pl][c * 256], 16, 0, 0);
    }
}

// ---- k_stats: per-(b,k) weighted sums + n ---------------------------------
__global__ __launch_bounds__(THREADS) void k_stats(
    const float* __restrict__ pred, const float* __restrict__ inp,
    const int* __restrict__ heart, float* __restrict__ sums)
{
    __shared__ float sbuf[8][CHUNK];        // 64 KB
    const int b     = blockIdx.x / BPB;
    const int chunk = blockIdx.x % BPB;
    const int tid   = threadIdx.x;
    const int wv    = tid >> 6, lane = tid & 63;

    stage_block(pred, inp, heart, b, chunk * CHUNK, sbuf, wv, lane);
    __syncthreads();

    float sacc[K_], tacc[K_][M_], uacc[K_][M_], nacc = 0.f;
    #pragma unroll
    for (int k = 0; k < K_; ++k) {
        sacc[k] = 0.f;
        #pragma unroll
        for (int m = 0; m < M_; ++m) { tacc[k][m] = 0.f; uacc[k][m] = 0.f; }
    }

    #pragma unroll
    for (int it = 0; it < CHUNK / 4 / THREADS; ++it) {
        const int v = it * THREADS + tid;           // float4 index
        const int4 h4 = ((const int4*)sbuf[7])[v];
        float4 pk[K_]; float4 xm[M_];
        #pragma unroll
        for (int k = 0; k < K_; ++k) pk[k] = ((const float4*)sbuf[k])[v];
        #pragma unroll
        for (int m = 0; m < M_; ++m) xm[m] = ((const float4*)sbuf[4 + m])[v];

        #define PIX1(C) do {                                                  \
            const float w = (h4.C == 1) ? 1.f : 0.f;                          \
            nacc += w;                                                        \
            _Pragma("unroll")                                                 \
            for (int k = 0; k < K_; ++k) {                                    \
                const float pw = pk[k].C * w;                                 \
                sacc[k] += pw;                                                \
                _Pragma("unroll")                                             \
                for (int m = 0; m < M_; ++m) {                                \
                    const float x = xm[m].C;                                  \
                    tacc[k][m] = fmaf(pw,     x, tacc[k][m]);                 \
                    uacc[k][m] = fmaf(pw * x, x, uacc[k][m]);                 \
                }                                                             \
            }                                                                 \
        } while (0)
        PIX1(x); PIX1(y); PIX1(z); PIX1(w);
        #undef PIX1
    }

    float acc[NACC];
    #pragma unroll
    for (int k = 0; k < K_; ++k) {
        acc[k] = sacc[k];
        #pragma unroll
        for (int m = 0; m < M_; ++m) {
            acc[4  + k * M_ + m] = tacc[k][m];
            acc[16 + k * M_ + m] = uacc[k][m];
        }
    }
    acc[28] = nacc;

    __syncthreads();                         // done reading sbuf; reuse it
    float* red = &sbuf[0][0];
    #pragma unroll
    for (int i = 0; i < NACC; ++i) {
        float x = acc[i];
        #pragma unroll
        for (int off = 32; off; off >>= 1) x += __shfl_down(x, off);
        if (lane == 0) red[wv * NACC + i] = x;
    }
    __syncthreads();
    if (tid < NACC) {
        const float x = red[tid] + red[NACC + tid] + red[2 * NACC + tid] + red[3 * NACC + tid];
        atomicAdd(&sums[b * NS + tid], x);
    }
}

// ---- k_loss: inline derivation + mixture log-likelihood -------------------
__global__ __launch_bounds__(THREADS) void k_loss(
    const float* __restrict__ pred, const float* __restrict__ inp,
    const int* __restrict__ heart, const float* __restrict__ sums,
    float* __restrict__ out)
{
    __shared__ float sbuf[8][CHUNK];        // 64 KB
    const int b     = blockIdx.x / BPB;
    const int chunk = blockIdx.x % BPB;
    const int tid   = threadIdx.x;
    const int wv    = tid >> 6, lane = tid & 63;

    stage_block(pred, inp, heart, b, chunk * CHUNK, sbuf, wv, lane);

    // per-thread derivation (broadcast reads, overlaps the staging)
    const float* sb = sums + b * NS;
    float mu[K_][M_], iv[K_][M_], ck[K_];
    #pragma unroll
    for (int k = 0; k < K_; ++k) {
        const float s = sb[k] + EPS;
        const float inv_s = 1.f / s;
        float c = 1.f;
        #pragma unroll
        for (int m = 0; m < M_; ++m) {
            const float t = sb[4  + k * M_ + m];
            const float u = sb[16 + k * M_ + m];
            const float muv = t * inv_s;
            const float var = fmaf(-muv, muv, u * inv_s) + EPS;
            mu[k][m] = muv;
            iv[k][m] = 0.5f / var;
            c *= rsqrtf(6.283185307179586f * var);
        }
        ck[k] = c;
    }
    const float invn = 1.f / (sb[28] * (float)B_);
    __syncthreads();

    float part = 0.f;
    #pragma unroll
    for (int it = 0; it < CHUNK / 4 / THREADS; ++it) {
        const int v = it * THREADS + tid;
        const int4 h4 = ((const int4*)sbuf[7])[v];
        float4 pk[K_]; float4 xm[M_];
        #pragma unroll
        for (int k = 0; k < K_; ++k) pk[k] = ((const float4*)sbuf[k])[v];
        #pragma unroll
        for (int m = 0; m < M_; ++m) xm[m] = ((const float4*)sbuf[4 + m])[v];

        #define PIX3(C) do {                                                  \
            const float w = (h4.C == 1) ? 1.f : 0.f;                          \
            float mix = EPS;                                                  \
            _Pragma("unroll")                                                 \
            for (int k = 0; k < K_; ++k) {                                    \
                float e = 0.f;                                                \
                _Pragma("unroll")                                             \
                for (int m = 0; m < M_; ++m) {                                \
                    const float d = xm[m].C - mu[k][m];                       \
                    e = fmaf(-(d * d), iv[k][m], e);                          \
                }                                                             \
                mix = fmaf(pk[k].C * ck[k], __expf(e), mix);                  \
            }                                                                 \
            part = fmaf(w, __logf(mix), part);                                \
        } while (0)
        PIX3(x); PIX3(y); PIX3(z); PIX3(w);
        #undef PIX3
    }

    __syncthreads();
    float* red = &sbuf[0][0];
    float x = part;
    #pragma unroll
    for (int off = 32; off; off >>= 1) x += __shfl_down(x, off);
    if (lane == 0) red[wv] = x;
    __syncthreads();
    if (tid == 0)
        atomicAdd(out, -(red[0] + red[1] + red[2] + red[3]) * invn);
}

// ---- k_probe: pure grid-stride float4 reader (m13 pattern), asm-sunk ------
__global__ __launch_bounds__(THREADS) void k_probe(
    const float* __restrict__ pred, const float* __restrict__ inp,
    const int* __restrict__ heart)
{
    const int gid = blockIdx.x * THREADS + threadIdx.x;
    const int gsz = gridDim.x * THREADS;

    const float4* p4 = (const float4*)pred;
    for (int i = gid; i < B_ * K_ * P_ / 4; i += gsz) {
        const float4 v = p4[i];
        asm volatile("" :: "v"(v.x), "v"(v.y), "v"(v.z), "v"(v.w));
    }
    const float4* i4 = (const float4*)inp;
    for (int i = gid; i < B_ * M_ * P_ / 4; i += gsz) {
        const float4 v = i4[i];
        asm volatile("" :: "v"(v.x), "v"(v.y), "v"(v.z), "v"(v.w));
    }
    const float4* h4 = (const float4*)heart;
    for (int i = gid; i < B_ * P_ / 4; i += gsz) {
        const float4 v = h4[i];
        asm volatile("" :: "v"(v.x), "v"(v.y), "v"(v.z), "v"(v.w));
    }
}

extern "C" void kernel_launch(void* const* d_in, const int* in_sizes, int n_in,
                              void* d_out, int out_size, void* d_ws, size_t ws_size,
                              hipStream_t stream)
{
    const float* pred  = (const float*)d_in[0];
    const float* inp   = (const float*)d_in[1];
    const int*   heart = (const int*)d_in[2];
    float* out  = (float*)d_out;
    float* sums = (float*)d_ws;            // B*32 floats

    hipMemsetAsync(sums, 0, B_ * NS * sizeof(float), stream);
    hipMemsetAsync(out,  0, sizeof(float), stream);

    k_stats<<<B_ * BPB, THREADS, 0, stream>>>(pred, inp, heart, sums);
    k_loss <<<B_ * BPB, THREADS, 0, stream>>>(pred, inp, heart, sums, out);
    k_probe<<<2048, THREADS, 0, stream>>>(pred, inp, heart);
}

// Round 9
// 76.103 us; speedup vs baseline: 1.4230x; 1.4230x over previous
//
#include <hip/hip_runtime.h>

#define EPS 1e-10f

constexpr int B_ = 64, K_ = 4, M_ = 3, P_ = 65536;
constexpr int THREADS = 256;
constexpr int CHUNK = 2048;                 // pixels per block (streaming passes)
constexpr int BPB = P_ / CHUNK;             // 32 -> 2048 blocks
constexpr int VPT = CHUNK / 4 / THREADS;    // 2 float4 iters per thread
constexpr int NS = 32;                      // sums stride: s0..3 t4..15 u16..27 n28
constexpr int NACC = 29;

// ---- k_stats: per-(b,k) weighted sums + ROI count --------------------------
__global__ __launch_bounds__(THREADS) void k_stats(
    const float* __restrict__ pred, const float* __restrict__ inp,
    const int* __restrict__ heart, float* __restrict__ sums)
{
    const int blk   = blockIdx.x;
    const int b     = blk / BPB;
    const int chunk = blk % BPB;
    const int tid   = threadIdx.x;

    const float4* pb = (const float4*)(pred + (size_t)b * K_ * P_);
    const float4* ib = (const float4*)(inp  + (size_t)b * M_ * P_);
    const int4*   hb = (const int4*)(heart + (size_t)b * P_);
    const int vbase = chunk * (CHUNK / 4);

    float sacc[K_], tacc[K_][M_], uacc[K_][M_], nacc = 0.f;
    #pragma unroll
    for (int k = 0; k < K_; ++k) {
        sacc[k] = 0.f;
        #pragma unroll
        for (int m = 0; m < M_; ++m) { tacc[k][m] = 0.f; uacc[k][m] = 0.f; }
    }

    #pragma unroll
    for (int it = 0; it < VPT; ++it) {
        const int v = vbase + it * THREADS + tid;
        const int4 h4 = hb[v];
        float4 pk[K_];
        float4 xm[M_];
        #pragma unroll
        for (int k = 0; k < K_; ++k) pk[k] = pb[k * (P_ / 4) + v];
        #pragma unroll
        for (int m = 0; m < M_; ++m) xm[m] = ib[m * (P_ / 4) + v];

        #define PIX1(C) do {                                                  \
            const float w = (h4.C == 1) ? 1.f : 0.f;                          \
            nacc += w;                                                        \
            _Pragma("unroll")                                                 \
            for (int k = 0; k < K_; ++k) {                                    \
                const float pw = pk[k].C * w;                                 \
                sacc[k] += pw;                                                \
                _Pragma("unroll")                                             \
                for (int m = 0; m < M_; ++m) {                                \
                    const float x = xm[m].C;                                  \
                    tacc[k][m] = fmaf(pw,     x, tacc[k][m]);                 \
                    uacc[k][m] = fmaf(pw * x, x, uacc[k][m]);                 \
                }                                                             \
            }                                                                 \
        } while (0)
        PIX1(x); PIX1(y); PIX1(z); PIX1(w);
        #undef PIX1
    }

    float acc[NACC];
    #pragma unroll
    for (int k = 0; k < K_; ++k) {
        acc[k] = sacc[k];
        #pragma unroll
        for (int m = 0; m < M_; ++m) {
            acc[4  + k * M_ + m] = tacc[k][m];
            acc[16 + k * M_ + m] = uacc[k][m];
        }
    }
    acc[28] = nacc;

    __shared__ float lds[4][NACC];
    const int lane = tid & 63, wid = tid >> 6;
    #pragma unroll
    for (int i = 0; i < NACC; ++i) {
        float x = acc[i];
        #pragma unroll
        for (int off = 32; off; off >>= 1) x += __shfl_down(x, off);
        if (lane == 0) lds[wid][i] = x;
    }
    __syncthreads();
    if (tid < NACC) {
        const float x = lds[0][tid] + lds[1][tid] + lds[2][tid] + lds[3][tid];
        atomicAdd(&sums[b * NS + tid], x);
    }
}

// ---- k_loss: inline derivation + mixture log-likelihood --------------------
__global__ __launch_bounds__(THREADS) void k_loss(
    const float* __restrict__ pred, const float* __restrict__ inp,
    const int* __restrict__ heart, const float* __restrict__ sums,
    float* __restrict__ out)
{
    const int blk   = blockIdx.x;
    const int b     = blk / BPB;
    const int chunk = blk % BPB;
    const int tid   = threadIdx.x;

    // per-thread derivation from the 29 broadcast sums (one cache line)
    const float* sb = sums + b * NS;
    float mu[K_][M_], iv[K_][M_], ck[K_];
    #pragma unroll
    for (int k = 0; k < K_; ++k) {
        const float s = sb[k] + EPS;
        const float inv_s = 1.f / s;
        float c = 1.f;
        #pragma unroll
        for (int m = 0; m < M_; ++m) {
            const float t = sb[4  + k * M_ + m];
            const float u = sb[16 + k * M_ + m];
            const float muv = t * inv_s;
            const float var = fmaf(-muv, muv, u * inv_s) + EPS;
            mu[k][m] = muv;
            iv[k][m] = 0.5f / var;
            c *= rsqrtf(6.283185307179586f * var);
        }
        ck[k] = c;
    }
    const float invn = 1.f / (sb[28] * (float)B_);

    const float4* pb = (const float4*)(pred + (size_t)b * K_ * P_);
    const float4* ib = (const float4*)(inp  + (size_t)b * M_ * P_);
    const int4*   hb = (const int4*)(heart + (size_t)b * P_);
    const int vbase = chunk * (CHUNK / 4);

    float part = 0.f;
    #pragma unroll
    for (int it = 0; it < VPT; ++it) {
        const int v = vbase + it * THREADS + tid;
        const int4 h4 = hb[v];
        float4 pk[K_];
        float4 xm[M_];
        #pragma unroll
        for (int k = 0; k < K_; ++k) pk[k] = pb[k * (P_ / 4) + v];
        #pragma unroll
        for (int m = 0; m < M_; ++m) xm[m] = ib[m * (P_ / 4) + v];

        #define PIX3(C) do {                                                  \
            const float w = (h4.C == 1) ? 1.f : 0.f;                          \
            float mix = EPS;                                                  \
            _Pragma("unroll")                                                 \
            for (int k = 0; k < K_; ++k) {                                    \
                float e = 0.f;                                                \
                _Pragma("unroll")                                             \
                for (int m = 0; m < M_; ++m) {                                \
                    const float d = xm[m].C - mu[k][m];                       \
                    e = fmaf(-(d * d), iv[k][m], e);                          \
                }                                                             \
                mix = fmaf(pk[k].C * ck[k], __expf(e), mix);                  \
            }                                                                 \
            part = fmaf(w, __logf(mix), part);                                \
        } while (0)
        PIX3(x); PIX3(y); PIX3(z); PIX3(w);
        #undef PIX3
    }

    __shared__ float lds[4];
    const int lane = tid & 63, wid = tid >> 6;
    float x = part;
    #pragma unroll
    for (int off = 32; off; off >>= 1) x += __shfl_down(x, off);
    if (lane == 0) lds[wid] = x;
    __syncthreads();
    if (tid == 0)
        atomicAdd(out, -(lds[0] + lds[1] + lds[2] + lds[3]) * invn);
}

extern "C" void kernel_launch(void* const* d_in, const int* in_sizes, int n_in,
                              void* d_out, int out_size, void* d_ws, size_t ws_size,
                              hipStream_t stream)
{
    const float* pred  = (const float*)d_in[0];
    const float* inp   = (const float*)d_in[1];
    const int*   heart = (const int*)d_in[2];
    float* out  = (float*)d_out;
    float* sums = (float*)d_ws;            // B*32 floats

    hipMemsetAsync(sums, 0, B_ * NS * sizeof(float), stream);
    hipMemsetAsync(out,  0, sizeof(float), stream);

    k_stats<<<B_ * BPB, THREADS, 0, stream>>>(pred, inp, heart, sums);
    k_loss <<<B_ * BPB, THREADS, 0, stream>>>(pred, inp, heart, sums, out);
}